// Round 1
// baseline (1465.253 us; speedup 1.0000x reference)
//
#include <hip/hip_runtime.h>

#define NTOT 16
#define CDIM 512
#define TDIM 2048
#define KCODE 1024
#define FH_ELEMS (NTOT * CDIM * TDIM)   // 16777216
#define M_TOTAL 61440                   // 16*(2048+1024+512+256)

typedef unsigned long long u64;
__device__ __forceinline__ u64 umin64(u64 a, u64 b) { return a < b ? a : b; }

// ---------------------------------------------------------------------------
// csq[k] = sum(codebook[k]^2)
__global__ __launch_bounds__(64) void csq_kernel(const float* __restrict__ cb,
                                                 float* __restrict__ csq) {
  const int code = blockIdx.x;
  const int t = threadIdx.x;
  const float* row = cb + (size_t)code * CDIM;
  float s = 0.f;
#pragma unroll
  for (int q = 0; q < 2; ++q) {
    float4 v = *(const float4*)(row + (t * 2 + q) * 4);
    s += v.x * v.x + v.y * v.y + v.z * v.z + v.w * v.w;
  }
#pragma unroll
  for (int off = 32; off; off >>= 1) s += __shfl_down(s, off, 64);
  if (t == 0) csq[code] = s;
}

// ---------------------------------------------------------------------------
// Distance GEMM + per-row argmin (packed u64 atomicMin).
// Block: 64 rows x 64 codes, grid.y = 16 code tiles. Pooling fused in A load.
template <int S>
__global__ __launch_bounds__(256) void gemm_argmin_kernel(
    const float* __restrict__ src,   // [N][C][T] residual (or x for S==1)
    const float* __restrict__ cb,    // [K][C]
    const float* __restrict__ csq,   // [K]
    u64* __restrict__ packed)        // [N*t_s] running (distkey<<32 | code)
{
  constexpr int t_s = TDIM / S;
  __shared__ float As[16][68];
  __shared__ float Bs[16][68];
  const int tid = threadIdx.x;
  const int tx = tid & 15, ty = tid >> 4;
  const int row_base = blockIdx.x * 64;
  const int n = row_base / t_s;
  const int t0 = row_base % t_s;
  const int code_base = blockIdx.y * 64;
  const float* srcn = src + (size_t)n * (CDIM * TDIM);
  const int lkk = tid >> 4;          // 0..15 : k within chunk
  const int lr4 = (tid & 15) * 4;    // 0..60 : row group
  const int bcr = tid >> 2;          // 0..63 : code within tile
  const int bkq = tid & 3;           // 0..3  : k quad

  float acc[4][4] = {};
  for (int kc = 0; kc < CDIM; kc += 16) {
    __syncthreads();
    {  // A tile: As[kk][r] = pooled flat[row_base+r][kc+kk]
      const float* p = srcn + (size_t)(kc + lkk) * TDIM + (t0 + lr4) * S;
      if (S == 1) {
        float4 v = *(const float4*)p;
        As[lkk][lr4 + 0] = v.x; As[lkk][lr4 + 1] = v.y;
        As[lkk][lr4 + 2] = v.z; As[lkk][lr4 + 3] = v.w;
      } else {
        float tmp[4] = {0.f, 0.f, 0.f, 0.f};
#pragma unroll
        for (int w4 = 0; w4 < S; ++w4) {
          float4 v = *(const float4*)(p + w4 * 4);
          tmp[(w4 * 4 + 0) / S] += v.x;
          tmp[(w4 * 4 + 1) / S] += v.y;
          tmp[(w4 * 4 + 2) / S] += v.z;
          tmp[(w4 * 4 + 3) / S] += v.w;
        }
        const float invS = 1.0f / (float)S;
        As[lkk][lr4 + 0] = tmp[0] * invS; As[lkk][lr4 + 1] = tmp[1] * invS;
        As[lkk][lr4 + 2] = tmp[2] * invS; As[lkk][lr4 + 3] = tmp[3] * invS;
      }
    }
    {  // B tile: Bs[kk][c] = cb[code_base+c][kc+kk]
      float4 v = *(const float4*)(cb + (size_t)(code_base + bcr) * CDIM + kc + bkq * 4);
      Bs[bkq * 4 + 0][bcr] = v.x; Bs[bkq * 4 + 1][bcr] = v.y;
      Bs[bkq * 4 + 2][bcr] = v.z; Bs[bkq * 4 + 3][bcr] = v.w;
    }
    __syncthreads();
#pragma unroll
    for (int kk = 0; kk < 16; ++kk) {
      float4 av = *(const float4*)&As[kk][ty * 4];
      float4 bv = *(const float4*)&Bs[kk][tx * 4];
      float a[4] = {av.x, av.y, av.z, av.w};
      float b[4] = {bv.x, bv.y, bv.z, bv.w};
#pragma unroll
      for (int i = 0; i < 4; ++i)
#pragma unroll
        for (int j = 0; j < 4; ++j) acc[i][j] = fmaf(a[i], b[j], acc[i][j]);
    }
  }

  u64 best[4] = {~0ull, ~0ull, ~0ull, ~0ull};
#pragma unroll
  for (int j = 0; j < 4; ++j) {
    const int code = code_base + tx * 4 + j;
    const float cs = csq[code];
#pragma unroll
    for (int i = 0; i < 4; ++i) {
      float d = fmaf(-2.0f, acc[i][j], cs);
      unsigned u = __float_as_uint(d);
      u = (u & 0x80000000u) ? ~u : (u | 0x80000000u);  // monotone float->uint
      best[i] = umin64(best[i], ((u64)u << 32) | (unsigned)code);
    }
  }
#pragma unroll
  for (int i = 0; i < 4; ++i) {
    u64 b = best[i];
#pragma unroll
    for (int off = 1; off < 16; off <<= 1) {
      unsigned lo = (unsigned)b, hi = (unsigned)(b >> 32);
      lo = (unsigned)__shfl_xor((int)lo, off, 64);
      hi = (unsigned)__shfl_xor((int)hi, off, 64);
      b = umin64(b, ((u64)hi << 32) | (u64)lo);
    }
    if (tx == 0) atomicMin(&packed[row_base + ty * 4 + i], b);
  }
}

// ---------------------------------------------------------------------------
// residual -= linear_upsample(codebook[idx]); also per-block sum(residual^2)
template <int S, bool FIRST>
__global__ __launch_bounds__(256) void upd_kernel(
    const float* __restrict__ x, float* __restrict__ resid,
    const float* __restrict__ cb, const u64* __restrict__ packed,  // [N*t_s]
    float* __restrict__ lossPart) {
  constexpr int t_s = TDIM / S;
  const int g = blockIdx.x * 256 + threadIdx.x;
  const int n = g >> 18;            // C*T/4 = 262144 per n
  const int rem = g & 262143;
  const int c = rem >> 9;           // T/4 = 512 per c
  const int t0 = (rem & 511) * 4;
  const u64* idxp = packed + n * t_s;
  const size_t base = (size_t)n * (CDIM * TDIM) + (size_t)c * TDIM + t0;
  float4 rv = *(const float4*)((FIRST ? x : (const float*)resid) + base);
  float r[4] = {rv.x, rv.y, rv.z, rv.w};
  float ss = 0.f;
#pragma unroll
  for (int j = 0; j < 4; ++j) {
    const int t = t0 + j;
    float up;
    if (S == 1) {
      int i0 = (int)(idxp[t] & 0xFFFFFFFFull);
      up = cb[(size_t)i0 * CDIM + c];
    } else {
      float pos = (t + 0.5f) * (1.0f / (float)S) - 0.5f;
      pos = fminf(fmaxf(pos, 0.0f), (float)(t_s - 1));
      int lo = (int)floorf(pos);
      int hi = min(lo + 1, t_s - 1);
      float w = pos - (float)lo;
      int i0 = (int)(idxp[lo] & 0xFFFFFFFFull);
      int i1 = (int)(idxp[hi] & 0xFFFFFFFFull);
      up = cb[(size_t)i0 * CDIM + c] * (1.0f - w) + cb[(size_t)i1 * CDIM + c] * w;
    }
    r[j] -= up;
    ss += r[j] * r[j];
  }
  float4 ov = {r[0], r[1], r[2], r[3]};
  *(float4*)(resid + base) = ov;

  __shared__ float red[4];
#pragma unroll
  for (int off = 32; off; off >>= 1) ss += __shfl_down(ss, off, 64);
  if ((threadIdx.x & 63) == 0) red[threadIdx.x >> 6] = ss;
  __syncthreads();
  if (threadIdx.x == 0)
    lossPart[blockIdx.x] = red[0] + red[1] + red[2] + red[3];
}

// ---------------------------------------------------------------------------
__global__ __launch_bounds__(256) void hist_kernel(const u64* __restrict__ packed,
                                                   int* __restrict__ hist) {
  const int i = blockIdx.x * 256 + threadIdx.x;  // 61440 total
  const int code = (int)(packed[i] & 0xFFFFFFFFull);
  atomicAdd(&hist[code], 1);
}

__global__ __launch_bounds__(256) void finalize_kernel(
    const float* __restrict__ lossPart, const int* __restrict__ hist,
    float* __restrict__ outTail) {
  __shared__ float red[4];
  const int tid = threadIdx.x;
  float s = 0.f;
  for (int i = tid; i < 4 * 16384; i += 256) s += lossPart[i];
#pragma unroll
  for (int off = 32; off; off >>= 1) s += __shfl_down(s, off, 64);
  if ((tid & 63) == 0) red[tid >> 6] = s;
  __syncthreads();
  const float loss =
      (red[0] + red[1] + red[2] + red[3]) * (1.0f / (4.0f * 16777216.0f));
  __syncthreads();
  float e = 0.f;
  for (int k = tid; k < KCODE; k += 256) {
    float p = (float)hist[k] * (1.0f / 61440.0f);
    e += p * logf(p + 1e-7f);
  }
#pragma unroll
  for (int off = 32; off; off >>= 1) e += __shfl_down(e, off, 64);
  if ((tid & 63) == 0) red[tid >> 6] = e;
  __syncthreads();
  if (tid == 0) {
    outTail[0] = loss;
    outTail[1] = expf(-(red[0] + red[1] + red[2] + red[3]));
  }
}

// f_hat = x - residual  (in place on the d_out region holding residual)
__global__ __launch_bounds__(256) void fhat_kernel(const float* __restrict__ x,
                                                   float* __restrict__ out) {
  const size_t i = ((size_t)blockIdx.x * 256 + threadIdx.x) * 4;
  float4 xv = *(const float4*)(x + i);
  float4 rv = *(const float4*)(out + i);
  float4 o = {xv.x - rv.x, xv.y - rv.y, xv.z - rv.z, xv.w - rv.w};
  *(float4*)(out + i) = o;
}

// ---------------------------------------------------------------------------
extern "C" void kernel_launch(void* const* d_in, const int* in_sizes, int n_in,
                              void* d_out, int out_size, void* d_ws,
                              size_t ws_size, hipStream_t stream) {
  const float* x = (const float*)d_in[0];
  const float* cb = (const float*)d_in[1];
  float* out = (float*)d_out;
  float* resid = out;  // f_hat region doubles as residual buffer

  char* ws = (char*)d_ws;
  u64* packed = (u64*)ws;                          // 61440 * 8 = 491520 B
  float* csq = (float*)(ws + 491520);              // 4096 B
  int* hist = (int*)(ws + 491520 + 4096);          // 4096 B
  float* lossPart = (float*)(ws + 491520 + 8192);  // 65536 * 4 = 262144 B

  hipMemsetAsync(packed, 0xFF, (size_t)M_TOTAL * 8, stream);
  hipMemsetAsync(hist, 0, KCODE * sizeof(int), stream);
  csq_kernel<<<KCODE, 64, 0, stream>>>(cb, csq);

  // packed-array per-scale offsets: rows = 16*t_s
  u64* p1 = packed;           // 32768 rows (t_s=2048)
  u64* p2 = packed + 32768;   // 16384 rows
  u64* p4 = packed + 49152;   //  8192 rows
  u64* p8 = packed + 57344;   //  4096 rows

  gemm_argmin_kernel<1><<<dim3(512, 16), 256, 0, stream>>>(x, cb, csq, p1);
  upd_kernel<1, true><<<16384, 256, 0, stream>>>(x, resid, cb, p1, lossPart);
  gemm_argmin_kernel<2><<<dim3(256, 16), 256, 0, stream>>>(resid, cb, csq, p2);
  upd_kernel<2, false><<<16384, 256, 0, stream>>>(x, resid, cb, p2,
                                                  lossPart + 16384);
  gemm_argmin_kernel<4><<<dim3(128, 16), 256, 0, stream>>>(resid, cb, csq, p4);
  upd_kernel<4, false><<<16384, 256, 0, stream>>>(x, resid, cb, p4,
                                                  lossPart + 2 * 16384);
  gemm_argmin_kernel<8><<<dim3(64, 16), 256, 0, stream>>>(resid, cb, csq, p8);
  upd_kernel<8, false><<<16384, 256, 0, stream>>>(x, resid, cb, p8,
                                                  lossPart + 3 * 16384);

  hist_kernel<<<240, 256, 0, stream>>>(packed, hist);
  finalize_kernel<<<1, 256, 0, stream>>>(lossPart, hist, out + FH_ELEMS);
  fhat_kernel<<<16384, 256, 0, stream>>>(x, out);
}

// Round 2
// 490.931 us; speedup vs baseline: 2.9846x; 2.9846x over previous
//
#include <hip/hip_runtime.h>

#define CDIM 512
#define TDIM 2048
#define KCODE 1024
#define NTOT 16
#define FH_ELEMS (NTOT * CDIM * TDIM)   // 16777216
#define M_TOTAL 61440                   // 16*(2048+1024+512+256)

typedef unsigned long long u64;
typedef unsigned int u32;
typedef __attribute__((ext_vector_type(8))) short s16x8;
typedef __attribute__((ext_vector_type(4))) float f32x4;
typedef __attribute__((ext_vector_type(2))) float f32x2;
typedef __attribute__((ext_vector_type(4))) int i32x4;

__device__ __forceinline__ u64 umin64(u64 a, u64 b) { return a < b ? a : b; }

// round-to-nearest-even fp32 -> bf16 bits
__device__ __forceinline__ u32 bf16_rne(float f) {
  u32 u = __float_as_uint(f);
  return (u + 0x7fffu + ((u >> 16) & 1u)) >> 16;
}
// pack hi/lo split: low16 = hi bf16 (k-unit 2c), high16 = lo bf16 (k-unit 2c+1)
__device__ __forceinline__ u32 split_pack(float v) {
  u32 hi = bf16_rne(v);
  float lo = v - __uint_as_float(hi << 16);
  return hi | (bf16_rne(lo) << 16);
}

// ---------------------------------------------------------------------------
// csq[k] = sum(codebook[k]^2)   (fp32, exact vs reference)
__global__ __launch_bounds__(64) void csq_kernel(const float* __restrict__ cb,
                                                 float* __restrict__ csq) {
  const int code = blockIdx.x;
  const int t = threadIdx.x;
  const float* row = cb + (size_t)code * CDIM;
  float s = 0.f;
#pragma unroll
  for (int q = 0; q < 2; ++q) {
    float4 v = *(const float4*)(row + (t * 2 + q) * 4);
    s += v.x * v.x + v.y * v.y + v.z * v.z + v.w * v.w;
  }
#pragma unroll
  for (int off = 32; off; off >>= 1) s += __shfl_down(s, off, 64);
  if (t == 0) csq[code] = s;
}

// ---------------------------------------------------------------------------
// Pre-split codebook into bf16 hi/lo (interleaved k-units: 2c=hi, 2c+1=lo),
// pre-tiled [code_tile 0..7][k_chunk 0..15][16384 B] and pre-XOR-swizzled so
// GEMM can global_load_lds it linearly and ds_read with byte^((row&7)<<4).
__global__ __launch_bounds__(256) void cbprep_kernel(const float* __restrict__ cb,
                                                     char* __restrict__ cb_pack) {
  const int g = blockIdx.x * 256 + threadIdx.x;  // 131072 threads x 16B = 2MB
  const int tile = g >> 10;                      // 1024 threads per 16KB tile
  const int L = (g & 1023) * 16;                 // byte offset within tile
  const int nt = tile >> 4, kc = tile & 15;
  const int code_local = L >> 7;
  const int kbyte = (L & 127) ^ ((code_local & 7) << 4);
  const int c_rel0 = kbyte >> 2;                 // 4 channels per 16B
  const int code = nt * 128 + code_local;
  const int c0 = kc * 32 + c_rel0;
  f32x4 v = *(const f32x4*)(cb + (size_t)code * CDIM + c0);
  i32x4 o;
#pragma unroll
  for (int j = 0; j < 4; ++j) o[j] = (int)split_pack(v[j]);
  *(i32x4*)(cb_pack + (size_t)g * 16) = o;
}

// ---------------------------------------------------------------------------
// MFMA distance GEMM + per-row argmin.
// D[code][m] = cb_split . x_split^T  (K=1024 bf16 = 512 channels hi/lo).
// Block: 128 m x 128 codes, BK=64 k-units, 4 waves (2 code x 2 m).
template <int S>
__global__ __launch_bounds__(256, 2) void gemm_argmin_kernel(
    const float* __restrict__ src,      // [N][C][T] residual (x for S==1)
    const char* __restrict__ cb_pack,   // pre-tiled swizzled split codebook
    const float* __restrict__ csq,      // [K]
    u64* __restrict__ packed)           // [16*t_s] running (distkey<<32|code)
{
  constexpr int t_s = TDIM / S;
  __shared__ __align__(16) char smem[16384 * 2 + 512];
  char* xs = smem;            // x tile  [128 m][64 ku] bf16, swizzled
  char* cbs = smem + 16384;   // cb tile [128 code][64 ku] bf16, swizzled
  float* csq_s = (float*)(smem + 32768);

  const int tid = threadIdx.x;
  const int lane = tid & 63;
  const int w = tid >> 6;
  const int row_base = blockIdx.x * 128;
  const int code_base = blockIdx.y * 128;
  const int n = row_base / t_s;
  const int t0 = row_base % t_s;
  const float* srcn = src + (size_t)n * (CDIM * TDIM);

  if (tid < 128) csq_s[tid] = csq[code_base + tid];

  const f32x4 zero = {0.f, 0.f, 0.f, 0.f};
  f32x4 acc[4][4];
#pragma unroll
  for (int fc = 0; fc < 4; ++fc)
#pragma unroll
    for (int fm = 0; fm < 4; ++fm) acc[fc][fm] = zero;

  const size_t cb_tile0 = ((size_t)blockIdx.y * 16) << 14;
  const int wc = w >> 1, wm = w & 1;

  for (int kc = 0; kc < 16; ++kc) {
    __syncthreads();
    {  // codebook tile: async global->LDS (pre-swizzled source, linear dest)
      const char* gsrc = cb_pack + cb_tile0 + ((size_t)kc << 14);
      char* ldst = cbs + (w << 10);
#pragma unroll
      for (int p = 0; p < 4; ++p) {
        __builtin_amdgcn_global_load_lds(
            (const __attribute__((address_space(1))) u32*)(gsrc + (p << 12) + (tid << 4)),
            (__attribute__((address_space(3))) u32*)(ldst + (p << 12)), 16, 0, 0);
      }
    }
    // x tile: pooled + hi/lo split, reg-staged, swizzled ds_write_b128
#pragma unroll
    for (int p = 0; p < 4; ++p) {
      const int idx = p * 4 + w;
      const int cg = idx >> 1;                  // 4-channel group 0..7
      const int m_local = (idx & 1) * 64 + lane;
      const float* xp = srcn + (size_t)(kc * 32 + cg * 4) * TDIM +
                        (size_t)(t0 + m_local) * S;
      u32 pk[4];
#pragma unroll
      for (int j = 0; j < 4; ++j) {
        float v;
        if constexpr (S == 1) {
          v = xp[j * TDIM];
        } else if constexpr (S == 2) {
          f32x2 t2 = *(const f32x2*)(xp + j * TDIM);
          v = (t2.x + t2.y) * 0.5f;
        } else if constexpr (S == 4) {
          f32x4 t4 = *(const f32x4*)(xp + j * TDIM);
          v = (t4.x + t4.y + t4.z + t4.w) * 0.25f;
        } else {
          f32x4 a4 = *(const f32x4*)(xp + j * TDIM);
          f32x4 b4 = *(const f32x4*)(xp + j * TDIM + 4);
          v = (a4.x + a4.y + a4.z + a4.w + b4.x + b4.y + b4.z + b4.w) * 0.125f;
        }
        pk[j] = split_pack(v);
      }
      i32x4 wv = {(int)pk[0], (int)pk[1], (int)pk[2], (int)pk[3]};
      *(i32x4*)(xs + ((m_local * 128 + cg * 16) ^ ((m_local & 7) << 4))) = wv;
    }
    __syncthreads();
    // compute: 2 k-steps x 16 MFMA
#pragma unroll
    for (int ks = 0; ks < 2; ++ks) {
      s16x8 af[4], bq[4];
#pragma unroll
      for (int fc = 0; fc < 4; ++fc) {
        const int row = wc * 64 + fc * 16 + (lane & 15);
        af[fc] = *(const s16x8*)(
            cbs + ((row * 128 + ks * 64 + (lane >> 4) * 16) ^ ((row & 7) << 4)));
      }
#pragma unroll
      for (int fm = 0; fm < 4; ++fm) {
        const int row = wm * 64 + fm * 16 + (lane & 15);
        bq[fm] = *(const s16x8*)(
            xs + ((row * 128 + ks * 64 + (lane >> 4) * 16) ^ ((row & 7) << 4)));
      }
#pragma unroll
      for (int fc = 0; fc < 4; ++fc)
#pragma unroll
        for (int fm = 0; fm < 4; ++fm)
          acc[fc][fm] = __builtin_amdgcn_mfma_f32_16x16x32_bf16(
              af[fc], bq[fm], acc[fc][fm], 0, 0, 0);
    }
  }

  // epilogue: d = csq - 2*dot; per-m argmin over this block's 128 codes
  u64 best[4] = {~0ull, ~0ull, ~0ull, ~0ull};
#pragma unroll
  for (int fc = 0; fc < 4; ++fc) {
#pragma unroll
    for (int r = 0; r < 4; ++r) {
      const int cl = wc * 64 + fc * 16 + (lane >> 4) * 4 + r;
      const float cs = csq_s[cl];
      const u64 codebits = (u32)(code_base + cl);
#pragma unroll
      for (int fm = 0; fm < 4; ++fm) {
        float d = fmaf(-2.0f, acc[fc][fm][r], cs);
        u32 u = __float_as_uint(d);
        u = (u & 0x80000000u) ? ~u : (u | 0x80000000u);  // monotone float->uint
        best[fm] = umin64(best[fm], ((u64)u << 32) | codebits);
      }
    }
  }
#pragma unroll
  for (int fm = 0; fm < 4; ++fm) {
    u64 b = best[fm];
#pragma unroll
    for (int off = 16; off < 64; off <<= 1) {
      u32 lo = (u32)b, hi = (u32)(b >> 32);
      lo = (u32)__shfl_xor((int)lo, off, 64);
      hi = (u32)__shfl_xor((int)hi, off, 64);
      b = umin64(b, ((u64)hi << 32) | lo);
    }
    if ((lane >> 4) == 0)
      atomicMin(&packed[row_base + wm * 64 + fm * 16 + (lane & 15)], b);
  }
}

// ---------------------------------------------------------------------------
// residual -= upsample(codebook[idx]); per-block sum(residual^2).
// Thread = 4 consecutive channels x 1 t -> float4 codebook gathers.
// LAST fuses f_hat = x - residual.
template <int S, bool FIRST, bool LAST>
__global__ __launch_bounds__(256) void upd_kernel(
    const float* __restrict__ x, float* __restrict__ resid,
    const float* __restrict__ cb, const u64* __restrict__ packed,
    float* __restrict__ lossPart) {
  constexpr int t_s = TDIM / S;
  const int tid = threadIdx.x, w = tid >> 6, lane = tid & 63;
  const int task = blockIdx.x * 4 + w;      // [n:16][cg:128][tg:32]
  const int t = (task & 31) * 64 + lane;
  const int cg = (task >> 5) & 127;
  const int n = task >> 12;
  const int c0 = cg * 4;
  const u64* idxp = packed + n * t_s;
  const size_t base = (size_t)n * (CDIM * TDIM) + (size_t)c0 * TDIM + t;

  f32x4 up;
  if constexpr (S == 1) {
    const int i0 = (int)(idxp[t] & 0xffffffffull);
    up = *(const f32x4*)(cb + (size_t)i0 * CDIM + c0);
  } else {
    float pos = (t + 0.5f) * (1.0f / (float)S) - 0.5f;
    pos = fminf(fmaxf(pos, 0.0f), (float)(t_s - 1));
    const int lo = (int)floorf(pos);
    const int hi = min(lo + 1, t_s - 1);
    const float wgt = pos - (float)lo;
    const int i0 = (int)(idxp[lo] & 0xffffffffull);
    const int i1 = (int)(idxp[hi] & 0xffffffffull);
    f32x4 a = *(const f32x4*)(cb + (size_t)i0 * CDIM + c0);
    f32x4 b = *(const f32x4*)(cb + (size_t)i1 * CDIM + c0);
    up = a * (1.0f - wgt) + b * wgt;
  }

  float ss = 0.f;
#pragma unroll
  for (int j = 0; j < 4; ++j) {
    const size_t a = base + (size_t)j * TDIM;
    float r = (FIRST ? x[a] : resid[a]) - up[j];
    ss += r * r;
    if constexpr (LAST)
      resid[a] = x[a] - r;   // f_hat
    else
      resid[a] = r;
  }

  __shared__ float red[4];
#pragma unroll
  for (int off = 32; off; off >>= 1) ss += __shfl_down(ss, off, 64);
  if (lane == 0) red[w] = ss;
  __syncthreads();
  if (tid == 0) lossPart[blockIdx.x] = red[0] + red[1] + red[2] + red[3];
}

// ---------------------------------------------------------------------------
__global__ __launch_bounds__(256) void hist_kernel(const u64* __restrict__ packed,
                                                   int* __restrict__ hist) {
  const int i = blockIdx.x * 256 + threadIdx.x;  // 61440 total
  const int code = (int)(packed[i] & 0xFFFFFFFFull);
  atomicAdd(&hist[code], 1);
}

__global__ __launch_bounds__(256) void finalize_kernel(
    const float* __restrict__ lossPart, const int* __restrict__ hist,
    float* __restrict__ outTail) {
  __shared__ float red[4];
  const int tid = threadIdx.x;
  float s = 0.f;
  for (int i = tid; i < 4 * 16384; i += 256) s += lossPart[i];
#pragma unroll
  for (int off = 32; off; off >>= 1) s += __shfl_down(s, off, 64);
  if ((tid & 63) == 0) red[tid >> 6] = s;
  __syncthreads();
  const float loss =
      (red[0] + red[1] + red[2] + red[3]) * (1.0f / (4.0f * 16777216.0f));
  __syncthreads();
  float e = 0.f;
  for (int k = tid; k < KCODE; k += 256) {
    float p = (float)hist[k] * (1.0f / 61440.0f);
    e += p * logf(p + 1e-7f);
  }
#pragma unroll
  for (int off = 32; off; off >>= 1) e += __shfl_down(e, off, 64);
  if ((tid & 63) == 0) red[tid >> 6] = e;
  __syncthreads();
  if (tid == 0) {
    outTail[0] = loss;
    outTail[1] = expf(-(red[0] + red[1] + red[2] + red[3]));
  }
}

// ---------------------------------------------------------------------------
extern "C" void kernel_launch(void* const* d_in, const int* in_sizes, int n_in,
                              void* d_out, int out_size, void* d_ws,
                              size_t ws_size, hipStream_t stream) {
  const float* x = (const float*)d_in[0];
  const float* cb = (const float*)d_in[1];
  float* out = (float*)d_out;
  float* resid = out;  // f_hat region doubles as residual buffer

  char* ws = (char*)d_ws;
  u64* packed = (u64*)ws;                       // 491520 B
  float* csq = (float*)(ws + 491520);           // 4096 B
  int* hist = (int*)(ws + 495616);              // 4096 B
  float* lossPart = (float*)(ws + 499712);      // 262144 B
  char* cb_pack = ws + 761856;                  // 2 MiB pre-split codebook

  hipMemsetAsync(packed, 0xFF, (size_t)M_TOTAL * 8, stream);
  hipMemsetAsync(hist, 0, KCODE * sizeof(int), stream);
  csq_kernel<<<KCODE, 64, 0, stream>>>(cb, csq);
  cbprep_kernel<<<512, 256, 0, stream>>>(cb, cb_pack);

  u64* p1 = packed;          // 32768 rows (t_s=2048)
  u64* p2 = packed + 32768;  // 16384 rows
  u64* p4 = packed + 49152;  //  8192 rows
  u64* p8 = packed + 57344;  //  4096 rows

  gemm_argmin_kernel<1><<<dim3(256, 8), 256, 0, stream>>>(x, cb_pack, csq, p1);
  upd_kernel<1, true, false><<<16384, 256, 0, stream>>>(x, resid, cb, p1, lossPart);
  gemm_argmin_kernel<2><<<dim3(128, 8), 256, 0, stream>>>(resid, cb_pack, csq, p2);
  upd_kernel<2, false, false><<<16384, 256, 0, stream>>>(x, resid, cb, p2,
                                                         lossPart + 16384);
  gemm_argmin_kernel<4><<<dim3(64, 8), 256, 0, stream>>>(resid, cb_pack, csq, p4);
  upd_kernel<4, false, false><<<16384, 256, 0, stream>>>(x, resid, cb, p4,
                                                         lossPart + 32768);
  gemm_argmin_kernel<8><<<dim3(32, 8), 256, 0, stream>>>(resid, cb_pack, csq, p8);
  upd_kernel<8, false, true><<<16384, 256, 0, stream>>>(x, resid, cb, p8,
                                                        lossPart + 49152);

  hist_kernel<<<240, 256, 0, stream>>>(packed, hist);
  finalize_kernel<<<1, 256, 0, stream>>>(lossPart, hist, out + FH_ELEMS);
}

// Round 3
// 457.635 us; speedup vs baseline: 3.2018x; 1.0728x over previous
//
#include <hip/hip_runtime.h>

#define CDIM 512
#define TDIM 2048
#define KCODE 1024
#define NTOT 16
#define FH_ELEMS (NTOT * CDIM * TDIM)   // 16777216
#define M_TOTAL 61440                   // 16*(2048+1024+512+256)

typedef unsigned long long u64;
typedef unsigned int u32;
typedef __attribute__((ext_vector_type(8))) short s16x8;
typedef __attribute__((ext_vector_type(4))) float f32x4;
typedef __attribute__((ext_vector_type(2))) float f32x2;
typedef __attribute__((ext_vector_type(4))) int i32x4;

__device__ __forceinline__ u64 umin64(u64 a, u64 b) { return a < b ? a : b; }

// round-to-nearest-even fp32 -> bf16 bits
__device__ __forceinline__ u32 bf16_rne(float f) {
  u32 u = __float_as_uint(f);
  return (u + 0x7fffu + ((u >> 16) & 1u)) >> 16;
}
// pack hi/lo split: low16 = hi bf16 (k-unit 2c), high16 = lo bf16 (k-unit 2c+1)
__device__ __forceinline__ u32 split_pack(float v) {
  u32 hi = bf16_rne(v);
  float lo = v - __uint_as_float(hi << 16);
  return hi | (bf16_rne(lo) << 16);
}
// byte offset of (m_local row, kbyte) inside a 16KB tile, XOR-swizzled
__device__ __forceinline__ int tile_addr(int ml, int kbyte) {
  return (ml * 128 + kbyte) ^ ((ml & 7) << 4);
}

// ---------------------------------------------------------------------------
// csq[k] = sum(codebook[k]^2)
__global__ __launch_bounds__(64) void csq_kernel(const float* __restrict__ cb,
                                                 float* __restrict__ csq) {
  const int code = blockIdx.x;
  const int t = threadIdx.x;
  const float* row = cb + (size_t)code * CDIM;
  float s = 0.f;
#pragma unroll
  for (int q = 0; q < 2; ++q) {
    float4 v = *(const float4*)(row + (t * 2 + q) * 4);
    s += v.x * v.x + v.y * v.y + v.z * v.z + v.w * v.w;
  }
#pragma unroll
  for (int off = 32; off; off >>= 1) s += __shfl_down(s, off, 64);
  if (t == 0) csq[code] = s;
}

// ---------------------------------------------------------------------------
// Pre-split codebook: tiled [code_tile 0..7][kc 0..15][16KB], XOR-swizzled.
__global__ __launch_bounds__(256) void cbprep_kernel(const float* __restrict__ cb,
                                                     char* __restrict__ cb_pack) {
  const int g = blockIdx.x * 256 + threadIdx.x;  // 131072 threads x 16B = 2MB
  const int tile = g >> 10;
  const int L = (g & 1023) * 16;
  const int nt = tile >> 4, kc = tile & 15;
  const int code_local = L >> 7;
  const int kbyte = (L & 127) ^ ((code_local & 7) << 4);
  const int c_rel0 = kbyte >> 2;
  const int code = nt * 128 + code_local;
  const int c0 = kc * 32 + c_rel0;
  f32x4 v = *(const f32x4*)(cb + (size_t)code * CDIM + c0);
  i32x4 o;
#pragma unroll
  for (int j = 0; j < 4; ++j) o[j] = (int)split_pack(v[j]);
  *(i32x4*)(cb_pack + (size_t)g * 16) = o;
}

// ---------------------------------------------------------------------------
// A1 = packed split of x, tiled [m_tile][kc][16KB] swizzled. Thread: 4c x 4t.
__global__ __launch_bounds__(256) void xprep_kernel(const float* __restrict__ x,
                                                    char* __restrict__ a1) {
  const int tid = threadIdx.x, w = tid >> 6, lane = tid & 63;
  const int task = blockIdx.x * 4 + w;  // [n:16][cg:128][tw:8]
  const int tw = task & 7;
  const int cg = (task >> 3) & 127;
  const int n = task >> 10;
  const int c0 = cg * 4;
  const int t0 = tw * 256 + lane * 4;
  const size_t base = (size_t)n * (CDIM * TDIM) + (size_t)c0 * TDIM + t0;
  u32 pk[4][4];  // [c][t]
#pragma unroll
  for (int j = 0; j < 4; ++j) {
    f32x4 v = *(const f32x4*)(x + base + j * TDIM);
#pragma unroll
    for (int tt = 0; tt < 4; ++tt) pk[j][tt] = split_pack(v[tt]);
  }
  const int kc = c0 >> 5, kbyte = (c0 & 31) * 4;
#pragma unroll
  for (int tt = 0; tt < 4; ++tt) {
    const int m = n * TDIM + t0 + tt;
    i32x4 o = {(int)pk[0][tt], (int)pk[1][tt], (int)pk[2][tt], (int)pk[3][tt]};
    *(i32x4*)(a1 + (((size_t)((m >> 7) * 16 + kc)) << 14) +
              tile_addr(m & 127, kbyte)) = o;
  }
}

// ---------------------------------------------------------------------------
// Scale-independent MFMA distance GEMM + argmin; both operands pre-packed.
__global__ __launch_bounds__(256, 4) void gemm_argmin_packed(
    const char* __restrict__ a_pack,   // [m_tiles][16][16KB]
    const char* __restrict__ cb_pack,  // [8][16][16KB]
    const float* __restrict__ csq,
    u64* __restrict__ packed) {
  __shared__ __align__(16) char smem[16384 * 2 + 512];
  char* xs = smem;
  char* cbs = smem + 16384;
  float* csq_s = (float*)(smem + 32768);

  const int tid = threadIdx.x;
  const int lane = tid & 63;
  const int w = tid >> 6;
  const int row_base = blockIdx.x * 128;
  const int code_base = blockIdx.y * 128;
  if (tid < 128) csq_s[tid] = csq[code_base + tid];

  const f32x4 zero = {0.f, 0.f, 0.f, 0.f};
  f32x4 acc[4][4];
#pragma unroll
  for (int fc = 0; fc < 4; ++fc)
#pragma unroll
    for (int fm = 0; fm < 4; ++fm) acc[fc][fm] = zero;

  const size_t a0 = ((size_t)blockIdx.x * 16) << 14;
  const size_t b0 = ((size_t)blockIdx.y * 16) << 14;
  const int wc = w >> 1, wm = w & 1;

  for (int kc = 0; kc < 16; ++kc) {
    __syncthreads();
    const char* gA = a_pack + a0 + ((size_t)kc << 14);
    const char* gB = cb_pack + b0 + ((size_t)kc << 14);
    char* la = xs + (w << 10);
    char* lb = cbs + (w << 10);
#pragma unroll
    for (int p = 0; p < 4; ++p) {
      __builtin_amdgcn_global_load_lds(
          (const __attribute__((address_space(1))) u32*)(gA + (p << 12) + (tid << 4)),
          (__attribute__((address_space(3))) u32*)(la + (p << 12)), 16, 0, 0);
      __builtin_amdgcn_global_load_lds(
          (const __attribute__((address_space(1))) u32*)(gB + (p << 12) + (tid << 4)),
          (__attribute__((address_space(3))) u32*)(lb + (p << 12)), 16, 0, 0);
    }
    __syncthreads();
#pragma unroll
    for (int ks = 0; ks < 2; ++ks) {
      s16x8 af[4], bq[4];
#pragma unroll
      for (int fc = 0; fc < 4; ++fc) {
        const int row = wc * 64 + fc * 16 + (lane & 15);
        af[fc] = *(const s16x8*)(cbs + tile_addr(row, ks * 64 + (lane >> 4) * 16));
      }
#pragma unroll
      for (int fm = 0; fm < 4; ++fm) {
        const int row = wm * 64 + fm * 16 + (lane & 15);
        bq[fm] = *(const s16x8*)(xs + tile_addr(row, ks * 64 + (lane >> 4) * 16));
      }
#pragma unroll
      for (int fc = 0; fc < 4; ++fc)
#pragma unroll
        for (int fm = 0; fm < 4; ++fm)
          acc[fc][fm] = __builtin_amdgcn_mfma_f32_16x16x32_bf16(
              af[fc], bq[fm], acc[fc][fm], 0, 0, 0);
    }
  }

  u64 best[4] = {~0ull, ~0ull, ~0ull, ~0ull};
#pragma unroll
  for (int fc = 0; fc < 4; ++fc) {
#pragma unroll
    for (int r = 0; r < 4; ++r) {
      const int cl = wc * 64 + fc * 16 + (lane >> 4) * 4 + r;
      const float cs = csq_s[cl];
      const u64 codebits = (u32)(code_base + cl);
#pragma unroll
      for (int fm = 0; fm < 4; ++fm) {
        float d = fmaf(-2.0f, acc[fc][fm][r], cs);
        u32 u = __float_as_uint(d);
        u = (u & 0x80000000u) ? ~u : (u | 0x80000000u);
        best[fm] = umin64(best[fm], ((u64)u << 32) | codebits);
      }
    }
  }
#pragma unroll
  for (int fm = 0; fm < 4; ++fm) {
    u64 b = best[fm];
#pragma unroll
    for (int off = 16; off < 64; off <<= 1) {
      u32 lo = (u32)b, hi = (u32)(b >> 32);
      lo = (u32)__shfl_xor((int)lo, off, 64);
      hi = (u32)__shfl_xor((int)hi, off, 64);
      b = umin64(b, ((u64)hi << 32) | lo);
    }
    if ((lane >> 4) == 0)
      atomicMin(&packed[row_base + wm * 64 + fm * 16 + (lane & 15)], b);
  }
}

// ---------------------------------------------------------------------------
// Fallback GEMM (R2): in-kernel staging from fp32 src, pooling+split fused.
template <int S>
__global__ __launch_bounds__(256, 2) void gemm_argmin_fused(
    const float* __restrict__ src, const char* __restrict__ cb_pack,
    const float* __restrict__ csq, u64* __restrict__ packed) {
  constexpr int t_s = TDIM / S;
  __shared__ __align__(16) char smem[16384 * 2 + 512];
  char* xs = smem;
  char* cbs = smem + 16384;
  float* csq_s = (float*)(smem + 32768);
  const int tid = threadIdx.x;
  const int lane = tid & 63;
  const int w = tid >> 6;
  const int row_base = blockIdx.x * 128;
  const int n = row_base / t_s;
  const int t0 = row_base % t_s;
  const int code_base = blockIdx.y * 128;
  const float* srcn = src + (size_t)n * (CDIM * TDIM);
  if (tid < 128) csq_s[tid] = csq[code_base + tid];
  const f32x4 zero = {0.f, 0.f, 0.f, 0.f};
  f32x4 acc[4][4];
#pragma unroll
  for (int fc = 0; fc < 4; ++fc)
#pragma unroll
    for (int fm = 0; fm < 4; ++fm) acc[fc][fm] = zero;
  const size_t cb_tile0 = ((size_t)blockIdx.y * 16) << 14;
  const int wc = w >> 1, wm = w & 1;
  for (int kc = 0; kc < 16; ++kc) {
    __syncthreads();
    {
      const char* gsrc = cb_pack + cb_tile0 + ((size_t)kc << 14);
      char* ldst = cbs + (w << 10);
#pragma unroll
      for (int p = 0; p < 4; ++p)
        __builtin_amdgcn_global_load_lds(
            (const __attribute__((address_space(1))) u32*)(gsrc + (p << 12) + (tid << 4)),
            (__attribute__((address_space(3))) u32*)(ldst + (p << 12)), 16, 0, 0);
    }
#pragma unroll
    for (int p = 0; p < 4; ++p) {
      const int idx = p * 4 + w;
      const int cg = idx >> 1;
      const int m_local = (idx & 1) * 64 + lane;
      const float* xp = srcn + (size_t)(kc * 32 + cg * 4) * TDIM +
                        (size_t)(t0 + m_local) * S;
      u32 pk[4];
#pragma unroll
      for (int j = 0; j < 4; ++j) {
        float v;
        if constexpr (S == 1) {
          v = xp[j * TDIM];
        } else if constexpr (S == 2) {
          f32x2 t2 = *(const f32x2*)(xp + j * TDIM);
          v = (t2.x + t2.y) * 0.5f;
        } else if constexpr (S == 4) {
          f32x4 t4 = *(const f32x4*)(xp + j * TDIM);
          v = (t4.x + t4.y + t4.z + t4.w) * 0.25f;
        } else {
          f32x4 a4 = *(const f32x4*)(xp + j * TDIM);
          f32x4 b4 = *(const f32x4*)(xp + j * TDIM + 4);
          v = (a4.x + a4.y + a4.z + a4.w + b4.x + b4.y + b4.z + b4.w) * 0.125f;
        }
        pk[j] = split_pack(v);
      }
      i32x4 wv = {(int)pk[0], (int)pk[1], (int)pk[2], (int)pk[3]};
      *(i32x4*)(xs + tile_addr(m_local, cg * 16)) = wv;
    }
    __syncthreads();
#pragma unroll
    for (int ks = 0; ks < 2; ++ks) {
      s16x8 af[4], bq[4];
#pragma unroll
      for (int fc = 0; fc < 4; ++fc) {
        const int row = wc * 64 + fc * 16 + (lane & 15);
        af[fc] = *(const s16x8*)(cbs + tile_addr(row, ks * 64 + (lane >> 4) * 16));
      }
#pragma unroll
      for (int fm = 0; fm < 4; ++fm) {
        const int row = wm * 64 + fm * 16 + (lane & 15);
        bq[fm] = *(const s16x8*)(xs + tile_addr(row, ks * 64 + (lane >> 4) * 16));
      }
#pragma unroll
      for (int fc = 0; fc < 4; ++fc)
#pragma unroll
        for (int fm = 0; fm < 4; ++fm)
          acc[fc][fm] = __builtin_amdgcn_mfma_f32_16x16x32_bf16(
              af[fc], bq[fm], acc[fc][fm], 0, 0, 0);
    }
  }
  u64 best[4] = {~0ull, ~0ull, ~0ull, ~0ull};
#pragma unroll
  for (int fc = 0; fc < 4; ++fc) {
#pragma unroll
    for (int r = 0; r < 4; ++r) {
      const int cl = wc * 64 + fc * 16 + (lane >> 4) * 4 + r;
      const float cs = csq_s[cl];
      const u64 codebits = (u32)(code_base + cl);
#pragma unroll
      for (int fm = 0; fm < 4; ++fm) {
        float d = fmaf(-2.0f, acc[fc][fm][r], cs);
        u32 u = __float_as_uint(d);
        u = (u & 0x80000000u) ? ~u : (u | 0x80000000u);
        best[fm] = umin64(best[fm], ((u64)u << 32) | codebits);
      }
    }
  }
#pragma unroll
  for (int fm = 0; fm < 4; ++fm) {
    u64 b = best[fm];
#pragma unroll
    for (int off = 16; off < 64; off <<= 1) {
      u32 lo = (u32)b, hi = (u32)(b >> 32);
      lo = (u32)__shfl_xor((int)lo, off, 64);
      hi = (u32)__shfl_xor((int)hi, off, 64);
      b = umin64(b, ((u64)hi << 32) | lo);
    }
    if ((lane >> 4) == 0)
      atomicMin(&packed[row_base + wm * 64 + fm * 16 + (lane & 15)], b);
  }
}

// ---------------------------------------------------------------------------
// residual update + loss partial + (optional) next-scale A-pack production.
// Thread: 4 consecutive channels x 4 consecutive t. LAST writes f_hat = x - r.
template <int S, bool FIRST, bool LAST, bool PACK>
__global__ __launch_bounds__(256) void upd_kernel(
    const float* __restrict__ x, float* __restrict__ resid,
    const float* __restrict__ cb, const u64* __restrict__ packed,
    float* __restrict__ lossPart, char* __restrict__ a_next) {
  constexpr int t_s = TDIM / S;   // source cells for upsample
  constexpr int SN = 2 * S;       // next-scale pool factor
  constexpr int t_n = TDIM / SN;  // rows per n in A_next
  const int tid = threadIdx.x, w = tid >> 6, lane = tid & 63;
  const int task = blockIdx.x * 4 + w;  // [n:16][cg:128][tw:8]
  const int tw = task & 7;
  const int cg = (task >> 3) & 127;
  const int n = task >> 10;
  const int c0 = cg * 4;
  const int t0 = tw * 256 + lane * 4;
  const u64* idxp = packed + n * t_s;
  const size_t base = (size_t)n * (CDIM * TDIM) + (size_t)c0 * TDIM + t0;

  f32x4 r[4];  // [channel] x 4t
#pragma unroll
  for (int j = 0; j < 4; ++j)
    r[j] = *(const f32x4*)((FIRST ? x : (const float*)resid) + base + j * TDIM);

#pragma unroll
  for (int tt = 0; tt < 4; ++tt) {
    const int t = t0 + tt;
    f32x4 upt;
    if constexpr (S == 1) {
      const int i0 = (int)(idxp[t] & 0xffffffffull);
      upt = *(const f32x4*)(cb + (size_t)i0 * CDIM + c0);
    } else {
      float pos = fminf(fmaxf((t + 0.5f) * (1.0f / (float)S) - 0.5f, 0.0f),
                        (float)(t_s - 1));
      const int lo = (int)pos;
      const int hi = min(lo + 1, t_s - 1);
      const float wgt = pos - (float)lo;
      const int i0 = (int)(idxp[lo] & 0xffffffffull);
      const int i1 = (int)(idxp[hi] & 0xffffffffull);
      f32x4 a = *(const f32x4*)(cb + (size_t)i0 * CDIM + c0);
      f32x4 b = *(const f32x4*)(cb + (size_t)i1 * CDIM + c0);
      upt = a * (1.0f - wgt) + b * wgt;
    }
#pragma unroll
    for (int j = 0; j < 4; ++j) r[j][tt] -= upt[j];
  }

  float ss = 0.f;
#pragma unroll
  for (int j = 0; j < 4; ++j)
#pragma unroll
    for (int tt = 0; tt < 4; ++tt) ss += r[j][tt] * r[j][tt];

#pragma unroll
  for (int j = 0; j < 4; ++j) {
    if constexpr (LAST) {
      f32x4 xv = *(const f32x4*)(x + base + j * TDIM);
      *(f32x4*)(resid + base + j * TDIM) = xv - r[j];  // f_hat
    } else {
      *(f32x4*)(resid + base + j * TDIM) = r[j];
    }
  }

  if constexpr (PACK) {
    const int kc = c0 >> 5, kbyte = (c0 & 31) * 4;
    if constexpr (SN == 2) {
#pragma unroll
      for (int q = 0; q < 2; ++q) {
        const int m = n * t_n + (t0 >> 1) + q;
        i32x4 o;
#pragma unroll
        for (int j = 0; j < 4; ++j)
          o[j] = (int)split_pack((r[j][q * 2] + r[j][q * 2 + 1]) * 0.5f);
        *(i32x4*)(a_next + (((size_t)((m >> 7) * 16 + kc)) << 14) +
                  tile_addr(m & 127, kbyte)) = o;
      }
    } else if constexpr (SN == 4) {
      const int m = n * t_n + (t0 >> 2);
      i32x4 o;
#pragma unroll
      for (int j = 0; j < 4; ++j)
        o[j] = (int)split_pack((r[j][0] + r[j][1] + r[j][2] + r[j][3]) * 0.25f);
      *(i32x4*)(a_next + (((size_t)((m >> 7) * 16 + kc)) << 14) +
                tile_addr(m & 127, kbyte)) = o;
    } else {  // SN == 8: pair lanes (t0 ^ 4)
      float s4[4];
#pragma unroll
      for (int j = 0; j < 4; ++j) s4[j] = r[j][0] + r[j][1] + r[j][2] + r[j][3];
      i32x4 o;
#pragma unroll
      for (int j = 0; j < 4; ++j) {
        float p = __shfl_xor(s4[j], 1, 64);
        o[j] = (int)split_pack((s4[j] + p) * 0.125f);
      }
      if ((lane & 1) == 0) {
        const int m = n * t_n + (t0 >> 3);
        *(i32x4*)(a_next + (((size_t)((m >> 7) * 16 + kc)) << 14) +
                  tile_addr(m & 127, kbyte)) = o;
      }
    }
  }

  __shared__ float red[4];
#pragma unroll
  for (int off = 32; off; off >>= 1) ss += __shfl_down(ss, off, 64);
  if (lane == 0) red[w] = ss;
  __syncthreads();
  if (tid == 0) lossPart[blockIdx.x] = red[0] + red[1] + red[2] + red[3];
}

// ---------------------------------------------------------------------------
__global__ __launch_bounds__(256) void hist_kernel(const u64* __restrict__ packed,
                                                   int* __restrict__ hist) {
  const int i = blockIdx.x * 256 + threadIdx.x;  // 61440 total
  const int code = (int)(packed[i] & 0xFFFFFFFFull);
  atomicAdd(&hist[code], 1);
}

__global__ __launch_bounds__(256) void finalize_kernel(
    const float* __restrict__ lossPart, const int* __restrict__ hist,
    float* __restrict__ outTail) {
  __shared__ float red[4];
  const int tid = threadIdx.x;
  float s = 0.f;
  for (int i = tid; i < 4 * 4096; i += 256) s += lossPart[i];
#pragma unroll
  for (int off = 32; off; off >>= 1) s += __shfl_down(s, off, 64);
  if ((tid & 63) == 0) red[tid >> 6] = s;
  __syncthreads();
  const float loss =
      (red[0] + red[1] + red[2] + red[3]) * (1.0f / (4.0f * 16777216.0f));
  __syncthreads();
  float e = 0.f;
  for (int k = tid; k < KCODE; k += 256) {
    float p = (float)hist[k] * (1.0f / 61440.0f);
    e += p * logf(p + 1e-7f);
  }
#pragma unroll
  for (int off = 32; off; off >>= 1) e += __shfl_down(e, off, 64);
  if ((tid & 63) == 0) red[tid >> 6] = e;
  __syncthreads();
  if (tid == 0) {
    outTail[0] = loss;
    outTail[1] = expf(-(red[0] + red[1] + red[2] + red[3]));
  }
}

// ---------------------------------------------------------------------------
extern "C" void kernel_launch(void* const* d_in, const int* in_sizes, int n_in,
                              void* d_out, int out_size, void* d_ws,
                              size_t ws_size, hipStream_t stream) {
  const float* x = (const float*)d_in[0];
  const float* cb = (const float*)d_in[1];
  float* out = (float*)d_out;
  float* resid = out;

  char* ws = (char*)d_ws;
  u64* packed = (u64*)ws;                   // 491520 B
  float* csq = (float*)(ws + 491520);       // 4096 B
  int* hist = (int*)(ws + 495616);          // 4096 B
  float* lossPart = (float*)(ws + 499712);  // 65536 B (4 x 4096)
  char* cb_pack = ws + 565248;              // 2 MiB
  char* a2 = ws + (4ull << 20);             // 32 MiB
  char* a4 = ws + (36ull << 20);            // 16 MiB
  char* a8 = ws + (52ull << 20);            // 8 MiB
  const size_t NEED_FAST = 60ull << 20;

  hipMemsetAsync(packed, 0xFF, (size_t)M_TOTAL * 8, stream);
  hipMemsetAsync(hist, 0, KCODE * sizeof(int), stream);
  csq_kernel<<<KCODE, 64, 0, stream>>>(cb, csq);
  cbprep_kernel<<<512, 256, 0, stream>>>(cb, cb_pack);

  u64* p1 = packed;          // 32768 rows (t_s=2048)
  u64* p2 = packed + 32768;  // 16384 rows
  u64* p4 = packed + 49152;  //  8192 rows
  u64* p8 = packed + 57344;  //  4096 rows

  if (ws_size >= NEED_FAST) {
    char* a1 = (char*)out;  // A1 pack lives in d_out until upd<1> overwrites
    xprep_kernel<<<4096, 256, 0, stream>>>(x, a1);
    gemm_argmin_packed<<<dim3(256, 8), 256, 0, stream>>>(a1, cb_pack, csq, p1);
    upd_kernel<1, true, false, true>
        <<<4096, 256, 0, stream>>>(x, resid, cb, p1, lossPart, a2);
    gemm_argmin_packed<<<dim3(128, 8), 256, 0, stream>>>(a2, cb_pack, csq, p2);
    upd_kernel<2, false, false, true>
        <<<4096, 256, 0, stream>>>(x, resid, cb, p2, lossPart + 4096, a4);
    gemm_argmin_packed<<<dim3(64, 8), 256, 0, stream>>>(a4, cb_pack, csq, p4);
    upd_kernel<4, false, false, true>
        <<<4096, 256, 0, stream>>>(x, resid, cb, p4, lossPart + 8192, a8);
    gemm_argmin_packed<<<dim3(32, 8), 256, 0, stream>>>(a8, cb_pack, csq, p8);
    upd_kernel<8, false, true, false>
        <<<4096, 256, 0, stream>>>(x, resid, cb, p8, lossPart + 12288, nullptr);
  } else {
    gemm_argmin_fused<1><<<dim3(256, 8), 256, 0, stream>>>(x, cb_pack, csq, p1);
    upd_kernel<1, true, false, false>
        <<<4096, 256, 0, stream>>>(x, resid, cb, p1, lossPart, nullptr);
    gemm_argmin_fused<2><<<dim3(128, 8), 256, 0, stream>>>(resid, cb_pack, csq, p2);
    upd_kernel<2, false, false, false>
        <<<4096, 256, 0, stream>>>(x, resid, cb, p2, lossPart + 4096, nullptr);
    gemm_argmin_fused<4><<<dim3(64, 8), 256, 0, stream>>>(resid, cb_pack, csq, p4);
    upd_kernel<4, false, false, false>
        <<<4096, 256, 0, stream>>>(x, resid, cb, p4, lossPart + 8192, nullptr);
    gemm_argmin_fused<8><<<dim3(32, 8), 256, 0, stream>>>(resid, cb_pack, csq, p8);
    upd_kernel<8, false, true, false>
        <<<4096, 256, 0, stream>>>(x, resid, cb, p8, lossPart + 12288, nullptr);
  }

  hist_kernel<<<240, 256, 0, stream>>>(packed, hist);
  finalize_kernel<<<1, 256, 0, stream>>>(lossPart, hist, out + FH_ELEMS);
}